// Round 15
// baseline (411.408 us; speedup 1.0000x reference)
//
#include <hip/hip_runtime.h>

#define TOK   32768
#define DM    768
#define KDIM  768
#define LSEQ  4096
#define NC    64
#define CL    64
#define NCHAIN 6144

typedef __bf16 bf16x8 __attribute__((ext_vector_type(8)));
typedef float  f32x4  __attribute__((ext_vector_type(4)));
typedef unsigned short u16;
typedef unsigned int u32;

__device__ __forceinline__ u16 f2bf(float f) {
  unsigned u = __builtin_bit_cast(unsigned, f);
  u += 0x7fffu + ((u >> 16) & 1u);
  return (u16)(u >> 16);
}
__device__ __forceinline__ float bf2f(u32 h) {
  unsigned u = (h & 0xffffu) << 16;
  return __builtin_bit_cast(float, u);
}

#define GLOAD_LDS16(g, l) __builtin_amdgcn_global_load_lds( \
    (const __attribute__((address_space(1))) void*)(g),     \
    (__attribute__((address_space(3))) void*)(l), 16, 0, 0)

// ---------------- fp32 -> bf16 weight convert ----------------
__global__ void cvt_k(const float* __restrict__ src, u16* __restrict__ dst, int n) {
  int i = blockIdx.x * 256 + threadIdx.x;
  if (i < n) dst[i] = f2bf(src[i]);
}

// ---------------- fp32 -> bf16 with zero padding ----------------
__global__ void cvt_pad_k(const float* __restrict__ src, u16* __restrict__ dst,
                          int rows, int cols, int dcols, int n) {
  int i = blockIdx.x * 256 + threadIdx.x;
  if (i >= n) return;
  int r = i / dcols, c = i % dcols;
  dst[i] = (r < rows && c < cols) ? f2bf(src[r * cols + c]) : (u16)0;
}

// ---------------- RMSNorm: x (fp32) -> xn (bf16), float4 path ----------------
__global__ __launch_bounds__(192)
void rmsnorm_k(const float* __restrict__ x, const float* __restrict__ w,
               u16* __restrict__ xnb) {
  long t = blockIdx.x;
  int tid = threadIdx.x;
  float4 v = ((const float4*)x)[t * 192 + tid];
  float s = v.x * v.x + v.y * v.y + v.z * v.z + v.w * v.w;
#pragma unroll
  for (int o = 32; o; o >>= 1) s += __shfl_down(s, o, 64);
  __shared__ float red[3];
  if ((tid & 63) == 0) red[tid >> 6] = s;
  __syncthreads();
  float sc = rsqrtf((red[0] + red[1] + red[2]) * (1.f / 768.f) + 1e-6f);
  float4 ww = ((const float4*)w)[tid];
  ushort4 o;
  o.x = f2bf(v.x * sc * ww.x);
  o.y = f2bf(v.y * sc * ww.y);
  o.z = f2bf(v.z * sc * ww.z);
  o.w = f2bf(v.w * sc * ww.w);
  ((ushort4*)xnb)[t * 192 + tid] = o;
}

// ======== wave-autonomous 64x64 GEMM: 1 wave/block, zero barriers ========
// C[m][n] = sum_k A[m][k]*B[n][k]; A,B bf16 row-major (lda/ldb), K%32==0.
// Theory (R12 audit): barrier-locked blocks leave every pipe <30% busy at
// 5.6K cy per K-step vs ~300 cy serial chain. Here each wave owns a private
// 64x64 tile + private 2x(4KB A + 4KB B) LDS -> NO s_barrier at all; pacing
// is per-wave: vmcnt(8) waits only stage(t) (stage(t+1)'s 8 loads stay in
// flight ~2 K-steps, covering L2 latency); explicit lgkmcnt(0) after the
// ds_reads makes re-staging the same buffer WAR-safe (writes land after
// issue). 16 KB LDS/block -> 10 blocks/CU. Swizzle pair = R12's proven
// mapping (0 conflicts): stage chunk c -> row c>>2, phys slot c&3, logical
// (c&3)^((c>>3)&3); read phys slot = kc ^ ((lr>>1)&3).
// Block swizzle (T1): xcd=bid&7 owns a row band; col-panel inner ->
// 96KB A-panel + B stay L2-resident.
// EPI: 0 fp32 C; 1 in_proj (conv+silu->o0, silu(z)->o1);
//      2 dt (bias+softplus->o0 bf16); 3 x_proj (o0 ld 64; 48/49->C fp32).
template <int EPI>
__global__ __launch_bounds__(64)
void gemmw(const u16* __restrict__ A, int lda,
           const u16* __restrict__ B, int ldb, int K,
           int GX, int RPX,
           float* __restrict__ C,
           const float* __restrict__ w0, const float* __restrict__ w1,
           u16* __restrict__ o0, u16* __restrict__ o1) {
  __shared__ __align__(16) u16 smA[2 * 2048];
  __shared__ __align__(16) u16 smB[2 * 2048];
  const int l = threadIdx.x;           // 0..63
  const int bid = blockIdx.x;
  const int xcd = bid & 7;
  const int p = bid >> 3;
  const long rowBase = (long)(xcd * RPX + p / GX) * 64;
  const long colBase = (long)(p % GX) * 64;

  const int lr = l & 15;
  const int kc = l >> 4;
  const int kcs = kc ^ ((lr >> 1) & 3);          // swizzled 16B slot for ds_read

  // staging: 4 chunks of 16B per matrix per lane (chunk c = l + 64*i):
  // row = (l>>2) + 16*i, logical slot = (l&3)^((l>>3)&3) (same for all i).
  const int srow = l >> 2;
  const int sslot = (l & 3) ^ ((l >> 3) & 3);
  const u16* gA = A + (rowBase + srow) * lda + sslot * 8;
  const u16* gB = B + (colBase + srow) * ldb + sslot * 8;

  f32x4 acc[4][4] = {};
  const int NT = K >> 5;

  auto STAGE = [&](int buf, int kt) {
    u16* bA = smA + buf * 2048;
    u16* bB = smB + buf * 2048;
#pragma unroll
    for (int i = 0; i < 4; ++i) {
      GLOAD_LDS16(gA + (long)(16 * i) * lda + kt, &bA[(l + 64 * i) * 8]);
      GLOAD_LDS16(gB + (long)(16 * i) * ldb + kt, &bB[(l + 64 * i) * 8]);
    }
  };

  STAGE(0, 0);
  if (NT > 1) STAGE(1, 32);

  for (int t = 0; t < NT; ++t) {
    // wait only our own stage(t); stage(t+1)'s 8 loads remain in flight
    if (t + 1 < NT) asm volatile("s_waitcnt vmcnt(8)" ::: "memory");
    else            asm volatile("s_waitcnt vmcnt(0)" ::: "memory");
    const u16* cA = smA + (t & 1) * 2048;
    const u16* cB = smB + (t & 1) * 2048;
    bf16x8 af[4], bfr[4];
#pragma unroll
    for (int m = 0; m < 4; ++m)
      af[m] = *(const bf16x8*)&cA[(m * 16 + lr) * 32 + kcs * 8];
#pragma unroll
    for (int n = 0; n < 4; ++n)
      bfr[n] = *(const bf16x8*)&cB[(n * 16 + lr) * 32 + kcs * 8];
    // reads complete before re-staging this buffer (WAR-safe: LDS writes
    // of the new stage cannot land before their issue, which is below)
    asm volatile("s_waitcnt lgkmcnt(0)" ::: "memory");
    if (t + 2 < NT) STAGE(t & 1, (t + 2) << 5);
#pragma unroll
    for (int m = 0; m < 4; ++m)
#pragma unroll
      for (int n = 0; n < 4; ++n)
        acc[m][n] = __builtin_amdgcn_mfma_f32_16x16x32_bf16(af[m], bfr[n], acc[m][n], 0, 0, 0);
  }

#pragma unroll
  for (int m = 0; m < 4; ++m)
#pragma unroll
    for (int n = 0; n < 4; ++n)
#pragma unroll
      for (int j = 0; j < 4; ++j) {
        long grow = rowBase + m * 16 + kc * 4 + j;
        long gcol = colBase + n * 16 + lr;
        float v = acc[m][n][j];
        if (EPI == 0) {
          C[grow * DM + gcol] = v;
        } else if (EPI == 1) {
          if (gcol < DM) {
            float t2 = v * w0[gcol] + w1[gcol];
            o0[grow * DM + gcol] = f2bf(t2 / (1.f + __expf(-t2)));
          } else {
            o1[grow * DM + (gcol - DM)] = f2bf(v / (1.f + __expf(-v)));
          }
        } else if (EPI == 2) {
          float t2 = v + w0[gcol];
          float d = (t2 > 20.f) ? t2 : __logf(1.f + __expf(t2));
          o0[grow * DM + gcol] = f2bf(d);
        } else {  // EPI == 3 (colBase == 0, gcol < 64 always)
          o0[grow * 64 + gcol] = f2bf(v);
          if (gcol == 48) C[grow * 2 + 0] = v;
          if (gcol == 49) C[grow * 2 + 1] = v;
        }
      }
}

// ---------------- selective scan (N_STATE=1), chunked 3-pass, 2 channels/thread ----
__global__ __launch_bounds__(384)
void scan1_k(const u16* __restrict__ deltab, const u16* __restrict__ xcb,
             const float* __restrict__ bmc, const float* __restrict__ A_log,
             float* __restrict__ aprod, float* __restrict__ hend) {
  int pe = threadIdx.x;
  int b = blockIdx.x, c = blockIdx.y;
  int e0 = pe * 2;
  float Ae0 = -__expf(A_log[e0]), Ae1 = -__expf(A_log[e0 + 1]);
  float ap0 = 1.f, h0 = 0.f, ap1 = 1.f, h1 = 0.f;
  long base = (long)b * LSEQ + (long)c * CL;
  for (int i = 0; i < CL; ++i) {
    long t = base + i;
    u32 dv = *(const u32*)&deltab[t * DM + e0];
    u32 xv = *(const u32*)&xcb[t * DM + e0];
    float Bm = bmc[t * 2];
    float d0 = bf2f(dv), d1 = bf2f(dv >> 16);
    float x0 = bf2f(xv), x1 = bf2f(xv >> 16);
    float a0 = __expf(d0 * Ae0), a1 = __expf(d1 * Ae1);
    ap0 *= a0; h0 = a0 * h0 + d0 * Bm * x0;
    ap1 *= a1; h1 = a1 * h1 + d1 * Bm * x1;
  }
  long chain = (long)c * NCHAIN + b * DM + e0;
  *(float2*)&aprod[chain] = make_float2(ap0, ap1);
  *(float2*)&hend[chain]  = make_float2(h0, h1);
}

__global__ __launch_bounds__(256)
void scan2_k(const float* __restrict__ aprod, const float* __restrict__ hend,
             float* __restrict__ carry) {
  int chain = blockIdx.x * 256 + threadIdx.x;
  float h = 0.f;
  for (int c = 0; c < NC; ++c) {
    carry[c * NCHAIN + chain] = h;
    h = aprod[c * NCHAIN + chain] * h + hend[c * NCHAIN + chain];
  }
}

__global__ __launch_bounds__(384)
void scan3_k(const u16* __restrict__ deltab, const u16* __restrict__ xcb,
             const float* __restrict__ bmc, const float* __restrict__ A_log,
             const float* __restrict__ Dp, const u16* __restrict__ szb,
             const float* __restrict__ carry, u16* __restrict__ ybf) {
  int pe = threadIdx.x;
  int b = blockIdx.x, c = blockIdx.y;
  int e0 = pe * 2;
  float Ae0 = -__expf(A_log[e0]), Ae1 = -__expf(A_log[e0 + 1]);
  float De0 = Dp[e0], De1 = Dp[e0 + 1];
  long chain = (long)c * NCHAIN + b * DM + e0;
  float2 hc = *(const float2*)&carry[chain];
  float h0 = hc.x, h1 = hc.y;
  long base = (long)b * LSEQ + (long)c * CL;
  for (int i = 0; i < CL; ++i) {
    long t = base + i;
    u32 dv = *(const u32*)&deltab[t * DM + e0];
    u32 xv = *(const u32*)&xcb[t * DM + e0];
    u32 sv = *(const u32*)&szb[t * DM + e0];
    float Bm = bmc[t * 2], Cc = bmc[t * 2 + 1];
    float d0 = bf2f(dv), d1 = bf2f(dv >> 16);
    float x0 = bf2f(xv), x1 = bf2f(xv >> 16);
    float a0 = __expf(d0 * Ae0), a1 = __expf(d1 * Ae1);
    h0 = a0 * h0 + d0 * Bm * x0;
    h1 = a1 * h1 + d1 * Bm * x1;
    float y0 = (h0 * Cc + De0 * x0) * bf2f(sv);
    float y1 = (h1 * Cc + De1 * x1) * bf2f(sv >> 16);
    *(u32*)&ybf[t * DM + e0] = (u32)f2bf(y0) | ((u32)f2bf(y1) << 16);
  }
}

// ---------------- launch ----------------
extern "C" void kernel_launch(void* const* d_in, const int* in_sizes, int n_in,
                              void* d_out, int out_size, void* d_ws, size_t ws_size,
                              hipStream_t stream) {
  const float* x         = (const float*)d_in[0];
  const float* rms_w     = (const float*)d_in[1];
  const float* in_proj_w = (const float*)d_in[2];
  const float* conv_w    = (const float*)d_in[3];
  const float* conv_b    = (const float*)d_in[4];
  const float* x_proj_w  = (const float*)d_in[5];
  const float* dt_proj_w = (const float*)d_in[6];
  const float* dt_proj_b = (const float*)d_in[7];
  const float* A_log     = (const float*)d_in[8];
  const float* Dp        = (const float*)d_in[9];
  const float* out_proj_w= (const float*)d_in[10];
  float* out = (float*)d_out;

  char* ws = (char*)d_ws;
  size_t off = 0;
  auto alloc = [&](size_t bytes) -> void* {
    void* p = ws + off;
    off += (bytes + 255) & ~(size_t)255;
    return p;
  };
  u16*   xnb    = (u16*)alloc((size_t)TOK * DM * 2);
  u16*   xcb    = (u16*)alloc((size_t)TOK * DM * 2);
  u16*   szb    = (u16*)alloc((size_t)TOK * DM * 2);
  u16*   ybf    = (u16*)alloc((size_t)TOK * DM * 2);
  u16*   deltab = (u16*)alloc((size_t)TOK * DM * 2);
  u16*   dbcb   = (u16*)alloc((size_t)TOK * 64 * 2);
  float* bmc    = (float*)alloc((size_t)TOK * 2 * 4);
  u16*   wInB   = (u16*)alloc((size_t)1536 * 768 * 2);
  u16*   wXpB   = (u16*)alloc((size_t)128 * 768 * 2);
  u16*   wDtB   = (u16*)alloc((size_t)768 * 64 * 2);
  u16*   wOutB  = (u16*)alloc((size_t)768 * 768 * 2);
  float* aprod  = (float*)alloc((size_t)NC * NCHAIN * 4);
  float* hend   = (float*)alloc((size_t)NC * NCHAIN * 4);
  float* carry  = (float*)alloc((size_t)NC * NCHAIN * 4);

  cvt_k<<<(1536 * 768 + 255) / 256, 256, 0, stream>>>(in_proj_w, wInB, 1536 * 768);
  cvt_k<<<(768 * 768 + 255) / 256, 256, 0, stream>>>(out_proj_w, wOutB, 768 * 768);
  cvt_pad_k<<<(128 * 768 + 255) / 256, 256, 0, stream>>>(x_proj_w, wXpB, 50, 768, 768, 128 * 768);
  cvt_pad_k<<<(768 * 64 + 255) / 256, 256, 0, stream>>>(dt_proj_w, wDtB, 768, 48, 64, 768 * 64);

  rmsnorm_k<<<TOK, 192, 0, stream>>>(x, rms_w, xnb);

  // xz = xn @ in_proj_w^T ; fused conv+silu -> xcb, silu(z) -> szb
  // grid 12288 = 8 XCDs x 64 row-panels(64) x 24 col-panels(64)
  gemmw<1><<<12288, 64, 0, stream>>>(
      xnb, DM, wInB, DM, KDIM, 24, 64, nullptr, conv_w, conv_b, xcb, szb);

  // dbc = xc @ x_proj_w^T (only cols 0..63 matter): delta_raw -> dbcb, Bm/C -> bmc
  // grid 512 = 8 x 64 x 1
  gemmw<3><<<512, 64, 0, stream>>>(
      xcb, DM, wXpB, DM, KDIM, 1, 64, bmc, nullptr, nullptr, dbcb, nullptr);

  // delta = softplus(dbc48 @ dt_proj_w^T + dt_b) -> bf16; grid 6144 = 8 x 64 x 12
  gemmw<2><<<6144, 64, 0, stream>>>(
      dbcb, 64, wDtB, 64, 64, 12, 64, nullptr, dt_proj_b, nullptr, deltab, nullptr);

  scan1_k<<<dim3(8, NC), 384, 0, stream>>>(deltab, xcb, bmc, A_log, aprod, hend);
  scan2_k<<<NCHAIN / 256, 256, 0, stream>>>(aprod, hend, carry);
  scan3_k<<<dim3(8, NC), 384, 0, stream>>>(deltab, xcb, bmc, A_log, Dp, szb, carry, ybf);

  // out = (y * silu(z)) @ out_proj_w^T; grid 6144 = 8 x 64 x 12
  gemmw<0><<<6144, 64, 0, stream>>>(
      ybf, DM, wOutB, DM, KDIM, 12, 64, out, nullptr, nullptr, nullptr, nullptr);
}

// Round 16
// 335.609 us; speedup vs baseline: 1.2259x; 1.2259x over previous
//
#include <hip/hip_runtime.h>

#define TOK   32768
#define DM    768
#define KDIM  768
#define LSEQ  4096
#define NC    64
#define CL    64
#define NCHAIN 6144

typedef __bf16 bf16x8 __attribute__((ext_vector_type(8)));
typedef float  f32x4  __attribute__((ext_vector_type(4)));
typedef float  f32x16 __attribute__((ext_vector_type(16)));
typedef unsigned short u16;
typedef unsigned int u32;

__device__ __forceinline__ u16 f2bf(float f) {
  unsigned u = __builtin_bit_cast(unsigned, f);
  u += 0x7fffu + ((u >> 16) & 1u);
  return (u16)(u >> 16);
}
__device__ __forceinline__ float bf2f(u32 h) {
  unsigned u = (h & 0xffffu) << 16;
  return __builtin_bit_cast(float, u);
}

#define GLOAD_LDS16(g, l) __builtin_amdgcn_global_load_lds( \
    (const __attribute__((address_space(1))) void*)(g),     \
    (__attribute__((address_space(3))) void*)(l), 16, 0, 0)

// ---------------- fp32 -> bf16 weight convert ----------------
__global__ void cvt_k(const float* __restrict__ src, u16* __restrict__ dst, int n) {
  int i = blockIdx.x * 256 + threadIdx.x;
  if (i < n) dst[i] = f2bf(src[i]);
}

// ---------------- fp32 -> bf16 with zero padding ----------------
__global__ void cvt_pad_k(const float* __restrict__ src, u16* __restrict__ dst,
                          int rows, int cols, int dcols, int n) {
  int i = blockIdx.x * 256 + threadIdx.x;
  if (i >= n) return;
  int r = i / dcols, c = i % dcols;
  dst[i] = (r < rows && c < cols) ? f2bf(src[r * cols + c]) : (u16)0;
}

// ---------------- RMSNorm: x (fp32) -> xn (bf16), float4 path ----------------
__global__ __launch_bounds__(192)
void rmsnorm_k(const float* __restrict__ x, const float* __restrict__ w,
               u16* __restrict__ xnb) {
  long t = blockIdx.x;
  int tid = threadIdx.x;
  float4 v = ((const float4*)x)[t * 192 + tid];
  float s = v.x * v.x + v.y * v.y + v.z * v.z + v.w * v.w;
#pragma unroll
  for (int o = 32; o; o >>= 1) s += __shfl_down(s, o, 64);
  __shared__ float red[3];
  if ((tid & 63) == 0) red[tid >> 6] = s;
  __syncthreads();
  float sc = rsqrtf((red[0] + red[1] + red[2]) * (1.f / 768.f) + 1e-6f);
  float4 ww = ((const float4*)w)[tid];
  ushort4 o;
  o.x = f2bf(v.x * sc * ww.x);
  o.y = f2bf(v.y * sc * ww.y);
  o.z = f2bf(v.z * sc * ww.z);
  o.w = f2bf(v.w * sc * ww.w);
  ((ushort4*)xnb)[t * 192 + tid] = o;
}

// ---------------- 128x128 BK=32 GEMM (R12 base), MFMA shape 32x32x16 ----------
// Identical to R12's gemm128 (2-buf 32KB LDS, stage-early, 1 barrier/K-step,
// both-sides swizzle, XCD chunking, launch_bounds(256,4)) EXCEPT the MFMA
// shape: per wave 64x64 = 2x2 tiles of 32x32, acc[2][2] x f32x16 (64 AGPR,
// unchanged). Per K-step: 8 MFMA (was 16), matrix-pipe 64cy (was 77cy,
// 2382 vs 2075 TF ubench), LDS reads unchanged (8 x b128/wave).
// A/B frag: row = l&31, k-chunk = (l>>5)*8 (16B contiguous, same as 16x16
// pattern). C/D (verified m74/m101): col = lane&31,
// row = (r&3) + 8*(r>>2) + 4*(lane>>5), r in [0,16).
// EPI: 0 fp32 C; 1 in_proj (conv+silu->o0, silu(z)->o1).
template <int EPI>
__global__ __launch_bounds__(256, 4)
void gemm128(const u16* __restrict__ A, int lda,
             const u16* __restrict__ B, int ldb, int K,
             int GX, int RPX,
             float* __restrict__ C,
             const float* __restrict__ w0, const float* __restrict__ w1,
             u16* __restrict__ o0, u16* __restrict__ o1) {
  __shared__ __align__(16) u16 smA[2 * 4096];
  __shared__ __align__(16) u16 smB[2 * 4096];
  const int tid = threadIdx.x;
  const int lane = tid & 63;
  const int wid = tid >> 6;

  const int bid = blockIdx.x;
  const int xcd = bid & 7;
  const int p = bid >> 3;
  const int colp = p % GX;
  const int rowp = xcd * RPX + p / GX;
  const long rowBase = (long)rowp * 128;
  const long colBase = (long)colp * 128;

  const int wr = (wid >> 1) * 64;
  const int wc = (wid & 1) * 64;
  const int l31 = lane & 31;
  const int l5 = lane >> 5;

  const int c1 = tid + 256;
  const u16* gA0 = A + (rowBase + (tid >> 2)) * lda + ((tid & 3) ^ ((tid >> 3) & 3)) * 8;
  const u16* gA1 = A + (rowBase + (c1 >> 2)) * lda + ((c1 & 3) ^ ((c1 >> 3) & 3)) * 8;
  const u16* gB0 = B + (colBase + (tid >> 2)) * ldb + ((tid & 3) ^ ((tid >> 3) & 3)) * 8;
  const u16* gB1 = B + (colBase + (c1 >> 2)) * ldb + ((c1 & 3) ^ ((c1 >> 3) & 3)) * 8;

  f32x16 acc[2][2] = {};
  const int NT = K >> 5;

  auto STAGE = [&](int buf, int kt) {
    u16* bA = smA + buf * 4096;
    u16* bB = smB + buf * 4096;
    GLOAD_LDS16(gA0 + kt, &bA[tid * 8]);
    GLOAD_LDS16(gA1 + kt, &bA[c1 * 8]);
    GLOAD_LDS16(gB0 + kt, &bB[tid * 8]);
    GLOAD_LDS16(gB1 + kt, &bB[c1 * 8]);
  };
  auto COMPUTE = [&](int buf) {
    const u16* cA = smA + buf * 4096;
    const u16* cB = smB + buf * 4096;
#pragma unroll
    for (int kh = 0; kh < 2; ++kh) {
      bf16x8 aF[2], bF[2];
#pragma unroll
      for (int mt = 0; mt < 2; ++mt) {
        int row = wr + mt * 32 + l31;
        int ps = (kh * 2 + l5) ^ ((row >> 1) & 3);
        aF[mt] = *(const bf16x8*)&cA[row * 32 + ps * 8];
      }
#pragma unroll
      for (int nt = 0; nt < 2; ++nt) {
        int row = wc + nt * 32 + l31;
        int ps = (kh * 2 + l5) ^ ((row >> 1) & 3);
        bF[nt] = *(const bf16x8*)&cB[row * 32 + ps * 8];
      }
#pragma unroll
      for (int mt = 0; mt < 2; ++mt)
#pragma unroll
        for (int nt = 0; nt < 2; ++nt)
          acc[mt][nt] = __builtin_amdgcn_mfma_f32_32x32x16_bf16(aF[mt], bF[nt], acc[mt][nt], 0, 0, 0);
    }
  };

  STAGE(0, 0);
  __syncthreads();

  for (int t = 0; t < NT; t += 2) {
    if (t + 1 < NT) STAGE(1, (t + 1) << 5);
    COMPUTE(0);
    __syncthreads();
    if (t + 2 < NT) STAGE(0, (t + 2) << 5);
    COMPUTE(1);
    __syncthreads();
  }

#pragma unroll
  for (int mt = 0; mt < 2; ++mt)
#pragma unroll
    for (int nt = 0; nt < 2; ++nt)
#pragma unroll
      for (int r = 0; r < 16; ++r) {
        long grow = rowBase + wr + mt * 32 + (r & 3) + 8 * (r >> 2) + 4 * l5;
        long gcol = colBase + wc + nt * 32 + l31;
        float v = acc[mt][nt][r];
        if (EPI == 0) {
          C[grow * DM + gcol] = v;
        } else {
          if (gcol < DM) {
            float t2 = v * w0[gcol] + w1[gcol];
            o0[grow * DM + gcol] = f2bf(t2 / (1.f + __expf(-t2)));
          } else {
            o1[grow * DM + (gcol - DM)] = f2bf(v / (1.f + __expf(-v)));
          }
        }
      }
}

// ---------------- BK=32 MFMA GEMM (x_proj / dt), 3-buffer, counted vmcnt ----------
// EPI: 2 dt (bias + fast softplus -> o0 bf16, stride DM);
//      3 x_proj (cols<64 -> o0 ld 64; cols 48/49 -> C fp32 at t*2+{0,1}).
template <int EPI>
__global__ __launch_bounds__(256)
void gemm32(const u16* __restrict__ A, int lda,
            const u16* __restrict__ B, int ldb, int K,
            int GX, int RPX,
            float* __restrict__ C,
            const float* __restrict__ w0,
            u16* __restrict__ o0) {
  __shared__ __align__(16) u16 smA[3 * 4096];
  __shared__ __align__(16) u16 smB[3 * 4096];
  const int tid = threadIdx.x;
  const int lane = tid & 63;
  const int wid = tid >> 6;

  const int bid = blockIdx.x;
  const int xcd = bid & 7;
  const int p = bid >> 3;
  const int colp = p % GX;
  const int rowp = xcd * RPX + p / GX;
  const long rowBase = (long)rowp * 128;
  const long colBase = (long)colp * 128;

  const int wr = (wid >> 1) * 64;
  const int wc = (wid & 1) * 64;
  const int lr = lane & 15;
  const int kc = lane >> 4;
  const int kcs = kc ^ ((lr >> 1) & 3);

  const int c1 = tid + 256;
  const u16* gA0 = A + (rowBase + (tid >> 2)) * lda + ((tid & 3) ^ ((tid >> 3) & 3)) * 8;
  const u16* gA1 = A + (rowBase + (c1 >> 2)) * lda + ((c1 & 3) ^ ((c1 >> 3) & 3)) * 8;
  const u16* gB0 = B + (colBase + (tid >> 2)) * ldb + ((tid & 3) ^ ((tid >> 3) & 3)) * 8;
  const u16* gB1 = B + (colBase + (c1 >> 2)) * ldb + ((c1 & 3) ^ ((c1 >> 3) & 3)) * 8;

  f32x4 acc[4][4] = {};
  const int NT = K >> 5;

  auto STAGE = [&](int buf, int kt) {
    u16* bA = smA + buf * 4096;
    u16* bB = smB + buf * 4096;
    GLOAD_LDS16(gA0 + kt, &bA[tid * 8]);
    GLOAD_LDS16(gA1 + kt, &bA[c1 * 8]);
    GLOAD_LDS16(gB0 + kt, &bB[tid * 8]);
    GLOAD_LDS16(gB1 + kt, &bB[c1 * 8]);
  };

  STAGE(0, 0);
  STAGE(1, 32);
  asm volatile("s_waitcnt vmcnt(4)" ::: "memory");
  __builtin_amdgcn_s_barrier();

  for (int t = 0; t < NT; ++t) {
    const u16* cA = smA + (t % 3) * 4096;
    const u16* cB = smB + (t % 3) * 4096;
    bf16x8 af[4], bfr[4];
#pragma unroll
    for (int m = 0; m < 4; ++m)
      af[m] = *(const bf16x8*)&cA[(wr + m * 16 + lr) * 32 + kcs * 8];
#pragma unroll
    for (int n = 0; n < 4; ++n)
      bfr[n] = *(const bf16x8*)&cB[(wc + n * 16 + lr) * 32 + kcs * 8];
    if (t + 2 < NT) STAGE((t + 2) % 3, (t + 2) << 5);
#pragma unroll
    for (int m = 0; m < 4; ++m)
#pragma unroll
      for (int n = 0; n < 4; ++n)
        acc[m][n] = __builtin_amdgcn_mfma_f32_16x16x32_bf16(af[m], bfr[n], acc[m][n], 0, 0, 0);
    if (t + 1 < NT) {
      if (t + 2 < NT) asm volatile("s_waitcnt vmcnt(4) lgkmcnt(0)" ::: "memory");
      else            asm volatile("s_waitcnt vmcnt(0) lgkmcnt(0)" ::: "memory");
      __builtin_amdgcn_s_barrier();
    }
  }

#pragma unroll
  for (int m = 0; m < 4; ++m)
#pragma unroll
    for (int n = 0; n < 4; ++n)
#pragma unroll
      for (int j = 0; j < 4; ++j) {
        long grow = rowBase + wr + m * 16 + kc * 4 + j;
        long gcol = colBase + wc + n * 16 + lr;
        float v = acc[m][n][j];
        if (EPI == 2) {
          float t = v + w0[gcol];
          float d = (t > 20.f) ? t : __logf(1.f + __expf(t));
          o0[grow * DM + gcol] = f2bf(d);
        } else {  // EPI == 3
          if (gcol < 64) o0[grow * 64 + gcol] = f2bf(v);
          if (gcol == 48) C[grow * 2 + 0] = v;
          if (gcol == 49) C[grow * 2 + 1] = v;
        }
      }
}

// ---------------- selective scan (N_STATE=1), chunked 3-pass, 2 channels/thread ----
__global__ __launch_bounds__(384)
void scan1_k(const u16* __restrict__ deltab, const u16* __restrict__ xcb,
             const float* __restrict__ bmc, const float* __restrict__ A_log,
             float* __restrict__ aprod, float* __restrict__ hend) {
  int pe = threadIdx.x;
  int b = blockIdx.x, c = blockIdx.y;
  int e0 = pe * 2;
  float Ae0 = -__expf(A_log[e0]), Ae1 = -__expf(A_log[e0 + 1]);
  float ap0 = 1.f, h0 = 0.f, ap1 = 1.f, h1 = 0.f;
  long base = (long)b * LSEQ + (long)c * CL;
  for (int i = 0; i < CL; ++i) {
    long t = base + i;
    u32 dv = *(const u32*)&deltab[t * DM + e0];
    u32 xv = *(const u32*)&xcb[t * DM + e0];
    float Bm = bmc[t * 2];
    float d0 = bf2f(dv), d1 = bf2f(dv >> 16);
    float x0 = bf2f(xv), x1 = bf2f(xv >> 16);
    float a0 = __expf(d0 * Ae0), a1 = __expf(d1 * Ae1);
    ap0 *= a0; h0 = a0 * h0 + d0 * Bm * x0;
    ap1 *= a1; h1 = a1 * h1 + d1 * Bm * x1;
  }
  long chain = (long)c * NCHAIN + b * DM + e0;
  *(float2*)&aprod[chain] = make_float2(ap0, ap1);
  *(float2*)&hend[chain]  = make_float2(h0, h1);
}

__global__ __launch_bounds__(256)
void scan2_k(const float* __restrict__ aprod, const float* __restrict__ hend,
             float* __restrict__ carry) {
  int chain = blockIdx.x * 256 + threadIdx.x;
  float h = 0.f;
  for (int c = 0; c < NC; ++c) {
    carry[c * NCHAIN + chain] = h;
    h = aprod[c * NCHAIN + chain] * h + hend[c * NCHAIN + chain];
  }
}

__global__ __launch_bounds__(384)
void scan3_k(const u16* __restrict__ deltab, const u16* __restrict__ xcb,
             const float* __restrict__ bmc, const float* __restrict__ A_log,
             const float* __restrict__ Dp, const u16* __restrict__ szb,
             const float* __restrict__ carry, u16* __restrict__ ybf) {
  int pe = threadIdx.x;
  int b = blockIdx.x, c = blockIdx.y;
  int e0 = pe * 2;
  float Ae0 = -__expf(A_log[e0]), Ae1 = -__expf(A_log[e0 + 1]);
  float De0 = Dp[e0], De1 = Dp[e0 + 1];
  long chain = (long)c * NCHAIN + b * DM + e0;
  float2 hc = *(const float2*)&carry[chain];
  float h0 = hc.x, h1 = hc.y;
  long base = (long)b * LSEQ + (long)c * CL;
  for (int i = 0; i < CL; ++i) {
    long t = base + i;
    u32 dv = *(const u32*)&deltab[t * DM + e0];
    u32 xv = *(const u32*)&xcb[t * DM + e0];
    u32 sv = *(const u32*)&szb[t * DM + e0];
    float Bm = bmc[t * 2], Cc = bmc[t * 2 + 1];
    float d0 = bf2f(dv), d1 = bf2f(dv >> 16);
    float x0 = bf2f(xv), x1 = bf2f(xv >> 16);
    float a0 = __expf(d0 * Ae0), a1 = __expf(d1 * Ae1);
    h0 = a0 * h0 + d0 * Bm * x0;
    h1 = a1 * h1 + d1 * Bm * x1;
    float y0 = (h0 * Cc + De0 * x0) * bf2f(sv);
    float y1 = (h1 * Cc + De1 * x1) * bf2f(sv >> 16);
    *(u32*)&ybf[t * DM + e0] = (u32)f2bf(y0) | ((u32)f2bf(y1) << 16);
  }
}

// ---------------- launch ----------------
extern "C" void kernel_launch(void* const* d_in, const int* in_sizes, int n_in,
                              void* d_out, int out_size, void* d_ws, size_t ws_size,
                              hipStream_t stream) {
  const float* x         = (const float*)d_in[0];
  const float* rms_w     = (const float*)d_in[1];
  const float* in_proj_w = (const float*)d_in[2];
  const float* conv_w    = (const float*)d_in[3];
  const float* conv_b    = (const float*)d_in[4];
  const float* x_proj_w  = (const float*)d_in[5];
  const float* dt_proj_w = (const float*)d_in[6];
  const float* dt_proj_b = (const float*)d_in[7];
  const float* A_log     = (const float*)d_in[8];
  const float* Dp        = (const float*)d_in[9];
  const float* out_proj_w= (const float*)d_in[10];
  float* out = (float*)d_out;

  char* ws = (char*)d_ws;
  size_t off = 0;
  auto alloc = [&](size_t bytes) -> void* {
    void* p = ws + off;
    off += (bytes + 255) & ~(size_t)255;
    return p;
  };
  u16*   xnb    = (u16*)alloc((size_t)TOK * DM * 2);
  u16*   xcb    = (u16*)alloc((size_t)TOK * DM * 2);
  u16*   szb    = (u16*)alloc((size_t)TOK * DM * 2);
  u16*   ybf    = (u16*)alloc((size_t)TOK * DM * 2);
  u16*   deltab = (u16*)alloc((size_t)TOK * DM * 2);
  u16*   dbcb   = (u16*)alloc((size_t)TOK * 64 * 2);
  float* bmc    = (float*)alloc((size_t)TOK * 2 * 4);
  u16*   wInB   = (u16*)alloc((size_t)1536 * 768 * 2);
  u16*   wXpB   = (u16*)alloc((size_t)128 * 768 * 2);
  u16*   wDtB   = (u16*)alloc((size_t)768 * 64 * 2);
  u16*   wOutB  = (u16*)alloc((size_t)768 * 768 * 2);
  float* aprod  = (float*)alloc((size_t)NC * NCHAIN * 4);
  float* hend   = (float*)alloc((size_t)NC * NCHAIN * 4);
  float* carry  = (float*)alloc((size_t)NC * NCHAIN * 4);

  cvt_k<<<(1536 * 768 + 255) / 256, 256, 0, stream>>>(in_proj_w, wInB, 1536 * 768);
  cvt_k<<<(768 * 768 + 255) / 256, 256, 0, stream>>>(out_proj_w, wOutB, 768 * 768);
  cvt_pad_k<<<(128 * 768 + 255) / 256, 256, 0, stream>>>(x_proj_w, wXpB, 50, 768, 768, 128 * 768);
  cvt_pad_k<<<(768 * 64 + 255) / 256, 256, 0, stream>>>(dt_proj_w, wDtB, 768, 48, 64, 768 * 64);

  rmsnorm_k<<<TOK, 192, 0, stream>>>(x, rms_w, xnb);

  // xz = xn @ in_proj_w^T ; fused conv+silu -> xcb, silu(z) -> szb
  // grid 3072 = 8 XCDs x 32 row-panels x 12 col-panels
  gemm128<1><<<3072, 256, 0, stream>>>(
      xnb, DM, wInB, DM, KDIM, 12, 32, nullptr, conv_w, conv_b, xcb, szb);

  // dbc = xc @ x_proj_w^T (rank-50, N pad 128): delta_raw -> dbcb, Bm/C -> bmc
  gemm32<3><<<256, 256, 0, stream>>>(
      xcb, DM, wXpB, DM, KDIM, 1, 32, bmc, nullptr, dbcb);

  // delta = softplus(dbc48 @ dt_proj_w^T + dt_b) -> bf16
  gemm32<2><<<1536, 256, 0, stream>>>(
      dbcb, 64, wDtB, 64, 64, 6, 32, nullptr, dt_proj_b, deltab);

  scan1_k<<<dim3(8, NC), 384, 0, stream>>>(deltab, xcb, bmc, A_log, aprod, hend);
  scan2_k<<<NCHAIN / 256, 256, 0, stream>>>(aprod, hend, carry);
  scan3_k<<<dim3(8, NC), 384, 0, stream>>>(deltab, xcb, bmc, A_log, Dp, szb, carry, ybf);

  // out = (y * silu(z)) @ out_proj_w^T; grid 1536 = 8 x 32 x 6
  gemm128<0><<<1536, 256, 0, stream>>>(
      ybf, DM, wOutB, DM, KDIM, 6, 32, out, nullptr, nullptr, nullptr, nullptr);
}

// Round 17
// 328.923 us; speedup vs baseline: 1.2508x; 1.0203x over previous
//
#include <hip/hip_runtime.h>

#define TOK   32768
#define DM    768
#define KDIM  768
#define LSEQ  4096
#define NC    64
#define CL    64
#define NCHAIN 6144

typedef __bf16 bf16x8 __attribute__((ext_vector_type(8)));
typedef float  f32x4  __attribute__((ext_vector_type(4)));
typedef unsigned short u16;
typedef unsigned int u32;

__device__ __forceinline__ u16 f2bf(float f) {
  unsigned u = __builtin_bit_cast(unsigned, f);
  u += 0x7fffu + ((u >> 16) & 1u);
  return (u16)(u >> 16);
}
__device__ __forceinline__ float bf2f(u32 h) {
  unsigned u = (h & 0xffffu) << 16;
  return __builtin_bit_cast(float, u);
}

#define GLOAD_LDS16(g, l) __builtin_amdgcn_global_load_lds( \
    (const __attribute__((address_space(1))) void*)(g),     \
    (__attribute__((address_space(3))) void*)(l), 16, 0, 0)

// ---------------- fp32 -> bf16 weight convert ----------------
__global__ void cvt_k(const float* __restrict__ src, u16* __restrict__ dst, int n) {
  int i = blockIdx.x * 256 + threadIdx.x;
  if (i < n) dst[i] = f2bf(src[i]);
}

// ---------------- fp32 -> bf16 with zero padding ----------------
__global__ void cvt_pad_k(const float* __restrict__ src, u16* __restrict__ dst,
                          int rows, int cols, int dcols, int n) {
  int i = blockIdx.x * 256 + threadIdx.x;
  if (i >= n) return;
  int r = i / dcols, c = i % dcols;
  dst[i] = (r < rows && c < cols) ? f2bf(src[r * cols + c]) : (u16)0;
}

// ---------------- RMSNorm: x (fp32) -> xn (bf16), float4 path ----------------
__global__ __launch_bounds__(192)
void rmsnorm_k(const float* __restrict__ x, const float* __restrict__ w,
               u16* __restrict__ xnb) {
  long t = blockIdx.x;
  int tid = threadIdx.x;
  float4 v = ((const float4*)x)[t * 192 + tid];
  float s = v.x * v.x + v.y * v.y + v.z * v.z + v.w * v.w;
#pragma unroll
  for (int o = 32; o; o >>= 1) s += __shfl_down(s, o, 64);
  __shared__ float red[3];
  if ((tid & 63) == 0) red[tid >> 6] = s;
  __syncthreads();
  float sc = rsqrtf((red[0] + red[1] + red[2]) * (1.f / 768.f) + 1e-6f);
  float4 ww = ((const float4*)w)[tid];
  ushort4 o;
  o.x = f2bf(v.x * sc * ww.x);
  o.y = f2bf(v.y * sc * ww.y);
  o.z = f2bf(v.z * sc * ww.z);
  o.w = f2bf(v.w * sc * ww.w);
  ((ushort4*)xnb)[t * 192 + tid] = o;
}

// ---------------- 128x128 BK=32 GEMM, 2-buf, tuned for 4 blocks/CU (R12) ----------
// C[m][n] = sum_k A[m][k]*B[n][k]; A,B bf16 row-major (lda/ldb), NT = K/32 even.
// 256 thr = 4 waves (2x2), wave = 64x64 (acc[4][4] = 64 AGPR).
// Best-of-12 structural variants: 4 blocks/CU (32KB LDS, VGPR 60),
// stage-early + one __syncthreads per K-step, both-sides conflict swizzle
// (phys 16B slot = logical ^ ((row>>1)&3); 0 conflicts), XCD-chunked blockIdx.
// Manual x2 unroll -> compile-time buffer selects.
// EPI: 0 fp32 C; 1 in_proj (conv+silu->o0, silu(z)->o1).
template <int EPI>
__global__ __launch_bounds__(256, 4)
void gemm128(const u16* __restrict__ A, int lda,
             const u16* __restrict__ B, int ldb, int K,
             int GX, int RPX,
             float* __restrict__ C,
             const float* __restrict__ w0, const float* __restrict__ w1,
             u16* __restrict__ o0, u16* __restrict__ o1) {
  __shared__ __align__(16) u16 smA[2 * 4096];
  __shared__ __align__(16) u16 smB[2 * 4096];
  const int tid = threadIdx.x;
  const int lane = tid & 63;
  const int wid = tid >> 6;

  const int bid = blockIdx.x;
  const int xcd = bid & 7;
  const int p = bid >> 3;
  const int colp = p % GX;
  const int rowp = xcd * RPX + p / GX;
  const long rowBase = (long)rowp * 128;
  const long colBase = (long)colp * 128;

  const int wr = (wid >> 1) * 64;
  const int wc = (wid & 1) * 64;
  const int lr = lane & 15;
  const int kc = lane >> 4;
  const int kcs = kc ^ ((lr >> 1) & 3);   // swizzled 16B slot for ds_read

  const int c1 = tid + 256;
  const u16* gA0 = A + (rowBase + (tid >> 2)) * lda + ((tid & 3) ^ ((tid >> 3) & 3)) * 8;
  const u16* gA1 = A + (rowBase + (c1 >> 2)) * lda + ((c1 & 3) ^ ((c1 >> 3) & 3)) * 8;
  const u16* gB0 = B + (colBase + (tid >> 2)) * ldb + ((tid & 3) ^ ((tid >> 3) & 3)) * 8;
  const u16* gB1 = B + (colBase + (c1 >> 2)) * ldb + ((c1 & 3) ^ ((c1 >> 3) & 3)) * 8;

  f32x4 acc[4][4] = {};
  const int NT = K >> 5;

  auto STAGE = [&](int buf, int kt) {
    u16* bA = smA + buf * 4096;
    u16* bB = smB + buf * 4096;
    GLOAD_LDS16(gA0 + kt, &bA[tid * 8]);
    GLOAD_LDS16(gA1 + kt, &bA[c1 * 8]);
    GLOAD_LDS16(gB0 + kt, &bB[tid * 8]);
    GLOAD_LDS16(gB1 + kt, &bB[c1 * 8]);
  };
  auto COMPUTE = [&](int buf) {
    const u16* cA = smA + buf * 4096;
    const u16* cB = smB + buf * 4096;
    bf16x8 af[4], bfr[4];
#pragma unroll
    for (int m = 0; m < 4; ++m)
      af[m] = *(const bf16x8*)&cA[(wr + m * 16 + lr) * 32 + kcs * 8];
#pragma unroll
    for (int n = 0; n < 4; ++n)
      bfr[n] = *(const bf16x8*)&cB[(wc + n * 16 + lr) * 32 + kcs * 8];
#pragma unroll
    for (int m = 0; m < 4; ++m)
#pragma unroll
      for (int n = 0; n < 4; ++n)
        acc[m][n] = __builtin_amdgcn_mfma_f32_16x16x32_bf16(af[m], bfr[n], acc[m][n], 0, 0, 0);
  };

  STAGE(0, 0);
  __syncthreads();

  // manual x2 unroll: buffer indices are compile-time constants
  for (int t = 0; t < NT; t += 2) {
    if (t + 1 < NT) STAGE(1, (t + 1) << 5);
    COMPUTE(0);
    __syncthreads();
    if (t + 2 < NT) STAGE(0, (t + 2) << 5);
    COMPUTE(1);
    __syncthreads();
  }

#pragma unroll
  for (int m = 0; m < 4; ++m)
#pragma unroll
    for (int n = 0; n < 4; ++n)
#pragma unroll
      for (int j = 0; j < 4; ++j) {
        long grow = rowBase + wr + m * 16 + kc * 4 + j;
        long gcol = colBase + wc + n * 16 + lr;
        float v = acc[m][n][j];
        if (EPI == 0) {
          C[grow * DM + gcol] = v;
        } else {
          if (gcol < DM) {
            float t2 = v * w0[gcol] + w1[gcol];
            o0[grow * DM + gcol] = f2bf(t2 / (1.f + __expf(-t2)));
          } else {
            o1[grow * DM + (gcol - DM)] = f2bf(v / (1.f + __expf(-v)));
          }
        }
      }
}

// ---------------- BK=32 MFMA GEMM (x_proj / dt), 3-buffer, counted vmcnt ----------
// EPI: 2 dt (bias + fast softplus -> o0 bf16, stride DM);
//      3 x_proj (cols<64 -> o0 ld 64; cols 48/49 -> C fp32 at t*2+{0,1}).
template <int EPI>
__global__ __launch_bounds__(256)
void gemm32(const u16* __restrict__ A, int lda,
            const u16* __restrict__ B, int ldb, int K,
            int GX, int RPX,
            float* __restrict__ C,
            const float* __restrict__ w0,
            u16* __restrict__ o0) {
  __shared__ __align__(16) u16 smA[3 * 4096];
  __shared__ __align__(16) u16 smB[3 * 4096];
  const int tid = threadIdx.x;
  const int lane = tid & 63;
  const int wid = tid >> 6;

  const int bid = blockIdx.x;
  const int xcd = bid & 7;
  const int p = bid >> 3;
  const int colp = p % GX;
  const int rowp = xcd * RPX + p / GX;
  const long rowBase = (long)rowp * 128;
  const long colBase = (long)colp * 128;

  const int wr = (wid >> 1) * 64;
  const int wc = (wid & 1) * 64;
  const int lr = lane & 15;
  const int kc = lane >> 4;
  const int kcs = kc ^ ((lr >> 1) & 3);

  const int c1 = tid + 256;
  const u16* gA0 = A + (rowBase + (tid >> 2)) * lda + ((tid & 3) ^ ((tid >> 3) & 3)) * 8;
  const u16* gA1 = A + (rowBase + (c1 >> 2)) * lda + ((c1 & 3) ^ ((c1 >> 3) & 3)) * 8;
  const u16* gB0 = B + (colBase + (tid >> 2)) * ldb + ((tid & 3) ^ ((tid >> 3) & 3)) * 8;
  const u16* gB1 = B + (colBase + (c1 >> 2)) * ldb + ((c1 & 3) ^ ((c1 >> 3) & 3)) * 8;

  f32x4 acc[4][4] = {};
  const int NT = K >> 5;

  auto STAGE = [&](int buf, int kt) {
    u16* bA = smA + buf * 4096;
    u16* bB = smB + buf * 4096;
    GLOAD_LDS16(gA0 + kt, &bA[tid * 8]);
    GLOAD_LDS16(gA1 + kt, &bA[c1 * 8]);
    GLOAD_LDS16(gB0 + kt, &bB[tid * 8]);
    GLOAD_LDS16(gB1 + kt, &bB[c1 * 8]);
  };

  STAGE(0, 0);
  STAGE(1, 32);
  asm volatile("s_waitcnt vmcnt(4)" ::: "memory");
  __builtin_amdgcn_s_barrier();

  for (int t = 0; t < NT; ++t) {
    const u16* cA = smA + (t % 3) * 4096;
    const u16* cB = smB + (t % 3) * 4096;
    bf16x8 af[4], bfr[4];
#pragma unroll
    for (int m = 0; m < 4; ++m)
      af[m] = *(const bf16x8*)&cA[(wr + m * 16 + lr) * 32 + kcs * 8];
#pragma unroll
    for (int n = 0; n < 4; ++n)
      bfr[n] = *(const bf16x8*)&cB[(wc + n * 16 + lr) * 32 + kcs * 8];
    if (t + 2 < NT) STAGE((t + 2) % 3, (t + 2) << 5);
#pragma unroll
    for (int m = 0; m < 4; ++m)
#pragma unroll
      for (int n = 0; n < 4; ++n)
        acc[m][n] = __builtin_amdgcn_mfma_f32_16x16x32_bf16(af[m], bfr[n], acc[m][n], 0, 0, 0);
    if (t + 1 < NT) {
      if (t + 2 < NT) asm volatile("s_waitcnt vmcnt(4) lgkmcnt(0)" ::: "memory");
      else            asm volatile("s_waitcnt vmcnt(0) lgkmcnt(0)" ::: "memory");
      __builtin_amdgcn_s_barrier();
    }
  }

#pragma unroll
  for (int m = 0; m < 4; ++m)
#pragma unroll
    for (int n = 0; n < 4; ++n)
#pragma unroll
      for (int j = 0; j < 4; ++j) {
        long grow = rowBase + wr + m * 16 + kc * 4 + j;
        long gcol = colBase + wc + n * 16 + lr;
        float v = acc[m][n][j];
        if (EPI == 2) {
          float t = v + w0[gcol];
          float d = (t > 20.f) ? t : __logf(1.f + __expf(t));
          o0[grow * DM + gcol] = f2bf(d);
        } else {  // EPI == 3
          if (gcol < 64) o0[grow * 64 + gcol] = f2bf(v);
          if (gcol == 48) C[grow * 2 + 0] = v;
          if (gcol == 49) C[grow * 2 + 1] = v;
        }
      }
}

// ---------------- selective scan (N_STATE=1), chunked 3-pass, 2 channels/thread ----
__global__ __launch_bounds__(384)
void scan1_k(const u16* __restrict__ deltab, const u16* __restrict__ xcb,
             const float* __restrict__ bmc, const float* __restrict__ A_log,
             float* __restrict__ aprod, float* __restrict__ hend) {
  int pe = threadIdx.x;
  int b = blockIdx.x, c = blockIdx.y;
  int e0 = pe * 2;
  float Ae0 = -__expf(A_log[e0]), Ae1 = -__expf(A_log[e0 + 1]);
  float ap0 = 1.f, h0 = 0.f, ap1 = 1.f, h1 = 0.f;
  long base = (long)b * LSEQ + (long)c * CL;
  for (int i = 0; i < CL; ++i) {
    long t = base + i;
    u32 dv = *(const u32*)&deltab[t * DM + e0];
    u32 xv = *(const u32*)&xcb[t * DM + e0];
    float Bm = bmc[t * 2];
    float d0 = bf2f(dv), d1 = bf2f(dv >> 16);
    float x0 = bf2f(xv), x1 = bf2f(xv >> 16);
    float a0 = __expf(d0 * Ae0), a1 = __expf(d1 * Ae1);
    ap0 *= a0; h0 = a0 * h0 + d0 * Bm * x0;
    ap1 *= a1; h1 = a1 * h1 + d1 * Bm * x1;
  }
  long chain = (long)c * NCHAIN + b * DM + e0;
  *(float2*)&aprod[chain] = make_float2(ap0, ap1);
  *(float2*)&hend[chain]  = make_float2(h0, h1);
}

__global__ __launch_bounds__(256)
void scan2_k(const float* __restrict__ aprod, const float* __restrict__ hend,
             float* __restrict__ carry) {
  int chain = blockIdx.x * 256 + threadIdx.x;
  float h = 0.f;
  for (int c = 0; c < NC; ++c) {
    carry[c * NCHAIN + chain] = h;
    h = aprod[c * NCHAIN + chain] * h + hend[c * NCHAIN + chain];
  }
}

__global__ __launch_bounds__(384)
void scan3_k(const u16* __restrict__ deltab, const u16* __restrict__ xcb,
             const float* __restrict__ bmc, const float* __restrict__ A_log,
             const float* __restrict__ Dp, const u16* __restrict__ szb,
             const float* __restrict__ carry, u16* __restrict__ ybf) {
  int pe = threadIdx.x;
  int b = blockIdx.x, c = blockIdx.y;
  int e0 = pe * 2;
  float Ae0 = -__expf(A_log[e0]), Ae1 = -__expf(A_log[e0 + 1]);
  float De0 = Dp[e0], De1 = Dp[e0 + 1];
  long chain = (long)c * NCHAIN + b * DM + e0;
  float2 hc = *(const float2*)&carry[chain];
  float h0 = hc.x, h1 = hc.y;
  long base = (long)b * LSEQ + (long)c * CL;
  for (int i = 0; i < CL; ++i) {
    long t = base + i;
    u32 dv = *(const u32*)&deltab[t * DM + e0];
    u32 xv = *(const u32*)&xcb[t * DM + e0];
    u32 sv = *(const u32*)&szb[t * DM + e0];
    float Bm = bmc[t * 2], Cc = bmc[t * 2 + 1];
    float d0 = bf2f(dv), d1 = bf2f(dv >> 16);
    float x0 = bf2f(xv), x1 = bf2f(xv >> 16);
    float a0 = __expf(d0 * Ae0), a1 = __expf(d1 * Ae1);
    h0 = a0 * h0 + d0 * Bm * x0;
    h1 = a1 * h1 + d1 * Bm * x1;
    float y0 = (h0 * Cc + De0 * x0) * bf2f(sv);
    float y1 = (h1 * Cc + De1 * x1) * bf2f(sv >> 16);
    *(u32*)&ybf[t * DM + e0] = (u32)f2bf(y0) | ((u32)f2bf(y1) << 16);
  }
}

// ---------------- launch ----------------
extern "C" void kernel_launch(void* const* d_in, const int* in_sizes, int n_in,
                              void* d_out, int out_size, void* d_ws, size_t ws_size,
                              hipStream_t stream) {
  const float* x         = (const float*)d_in[0];
  const float* rms_w     = (const float*)d_in[1];
  const float* in_proj_w = (const float*)d_in[2];
  const float* conv_w    = (const float*)d_in[3];
  const float* conv_b    = (const float*)d_in[4];
  const float* x_proj_w  = (const float*)d_in[5];
  const float* dt_proj_w = (const float*)d_in[6];
  const float* dt_proj_b = (const float*)d_in[7];
  const float* A_log     = (const float*)d_in[8];
  const float* Dp        = (const float*)d_in[9];
  const float* out_proj_w= (const float*)d_in[10];
  float* out = (float*)d_out;

  char* ws = (char*)d_ws;
  size_t off = 0;
  auto alloc = [&](size_t bytes) -> void* {
    void* p = ws + off;
    off += (bytes + 255) & ~(size_t)255;
    return p;
  };
  u16*   xnb    = (u16*)alloc((size_t)TOK * DM * 2);
  u16*   xcb    = (u16*)alloc((size_t)TOK * DM * 2);
  u16*   szb    = (u16*)alloc((size_t)TOK * DM * 2);
  u16*   ybf    = (u16*)alloc((size_t)TOK * DM * 2);
  u16*   deltab = (u16*)alloc((size_t)TOK * DM * 2);
  u16*   dbcb   = (u16*)alloc((size_t)TOK * 64 * 2);
  float* bmc    = (float*)alloc((size_t)TOK * 2 * 4);
  u16*   wInB   = (u16*)alloc((size_t)1536 * 768 * 2);
  u16*   wXpB   = (u16*)alloc((size_t)128 * 768 * 2);
  u16*   wDtB   = (u16*)alloc((size_t)768 * 64 * 2);
  u16*   wOutB  = (u16*)alloc((size_t)768 * 768 * 2);
  float* aprod  = (float*)alloc((size_t)NC * NCHAIN * 4);
  float* hend   = (float*)alloc((size_t)NC * NCHAIN * 4);
  float* carry  = (float*)alloc((size_t)NC * NCHAIN * 4);

  cvt_k<<<(1536 * 768 + 255) / 256, 256, 0, stream>>>(in_proj_w, wInB, 1536 * 768);
  cvt_k<<<(768 * 768 + 255) / 256, 256, 0, stream>>>(out_proj_w, wOutB, 768 * 768);
  cvt_pad_k<<<(128 * 768 + 255) / 256, 256, 0, stream>>>(x_proj_w, wXpB, 50, 768, 768, 128 * 768);
  cvt_pad_k<<<(768 * 64 + 255) / 256, 256, 0, stream>>>(dt_proj_w, wDtB, 768, 48, 64, 768 * 64);

  rmsnorm_k<<<TOK, 192, 0, stream>>>(x, rms_w, xnb);

  // xz = xn @ in_proj_w^T ; fused conv+silu -> xcb, silu(z) -> szb
  // grid 3072 = 8 XCDs x 32 row-panels x 12 col-panels
  gemm128<1><<<3072, 256, 0, stream>>>(
      xnb, DM, wInB, DM, KDIM, 12, 32, nullptr, conv_w, conv_b, xcb, szb);

  // dbc = xc @ x_proj_w^T (rank-50, N pad 128): delta_raw -> dbcb, Bm/C -> bmc
  gemm32<3><<<256, 256, 0, stream>>>(
      xcb, DM, wXpB, DM, KDIM, 1, 32, bmc, nullptr, dbcb);

  // delta = softplus(dbc48 @ dt_proj_w^T + dt_b) -> bf16
  gemm32<2><<<1536, 256, 0, stream>>>(
      dbcb, 64, wDtB, 64, 64, 6, 32, nullptr, dt_proj_b, deltab);

  scan1_k<<<dim3(8, NC), 384, 0, stream>>>(deltab, xcb, bmc, A_log, aprod, hend);
  scan2_k<<<NCHAIN / 256, 256, 0, stream>>>(aprod, hend, carry);
  scan3_k<<<dim3(8, NC), 384, 0, stream>>>(deltab, xcb, bmc, A_log, Dp, szb, carry, ybf);

  // out = (y * silu(z)) @ out_proj_w^T; grid 1536 = 8 x 32 x 6
  gemm128<0><<<1536, 256, 0, stream>>>(
      ybf, DM, wOutB, DM, KDIM, 6, 32, out, nullptr, nullptr, nullptr, nullptr);
}